// Round 1
// baseline (4145.332 us; speedup 1.0000x reference)
//
#include <hip/hip_runtime.h>
#include <hip/hip_bf16.h>

// Problem constants
#define BATCH 4
#define SEQ   2048
#define DIM   1024
#define NHEAD 16
#define HDIM  64
#define ROWS  (BATCH * SEQ)        // 8192
#define SCALE 0.125f               // 64^-0.5

// ---------------------------------------------------------------------------
// Tiled fp32 GEMM: C[M,N] = A[M,K] @ B[K,N] + bias[N]
// mode 0: scatter into Q/K/V bf16 buffers laid out [B,H,N,HDIM]
// mode 1: plain row-major fp32 store to Cout
// Block: 16x16 threads, 64x64 tile, 4x4 per-thread, K-step 16.
// ---------------------------------------------------------------------------
__global__ __launch_bounds__(256)
void gemm_bias_kernel(const float* __restrict__ A, const float* __restrict__ B,
                      const float* __restrict__ bias,
                      int M, int N, int K, int mode,
                      __hip_bfloat16* __restrict__ Qb,
                      __hip_bfloat16* __restrict__ Kb,
                      __hip_bfloat16* __restrict__ Vb,
                      float* __restrict__ Cout) {
    const int tx = threadIdx.x, ty = threadIdx.y;
    const int t = ty * 16 + tx;
    const int row0 = blockIdx.y * 64;
    const int col0 = blockIdx.x * 64;

    __shared__ float As[16][65];   // As[kk][i] = A[row0+i][k0+kk]
    __shared__ float Bs[16][65];   // Bs[kk][j] = B[k0+kk][col0+j]

    float acc[4][4];
#pragma unroll
    for (int i = 0; i < 4; ++i)
#pragma unroll
        for (int j = 0; j < 4; ++j) acc[i][j] = 0.f;

    for (int k0 = 0; k0 < K; k0 += 16) {
#pragma unroll
        for (int e = 0; e < 4; ++e) {
            int idx = e * 256 + t;
            {   // A: 64 rows x 16 k
                int i = idx >> 4, kk = idx & 15;
                As[kk][i] = A[(long)(row0 + i) * K + (k0 + kk)];
            }
            {   // B: 16 k x 64 cols
                int kk = idx >> 6, j = idx & 63;
                Bs[kk][j] = B[(long)(k0 + kk) * N + (col0 + j)];
            }
        }
        __syncthreads();
#pragma unroll
        for (int kk = 0; kk < 16; ++kk) {
            float a[4], b[4];
#pragma unroll
            for (int i = 0; i < 4; ++i) a[i] = As[kk][ty * 4 + i];
#pragma unroll
            for (int j = 0; j < 4; ++j) b[j] = Bs[kk][tx * 4 + j];
#pragma unroll
            for (int i = 0; i < 4; ++i)
#pragma unroll
                for (int j = 0; j < 4; ++j) acc[i][j] += a[i] * b[j];
        }
        __syncthreads();
    }

#pragma unroll
    for (int i = 0; i < 4; ++i) {
#pragma unroll
        for (int j = 0; j < 4; ++j) {
            int row = row0 + ty * 4 + i;
            int c = col0 + tx * 4 + j;
            float v = acc[i][j] + bias[c];
            if (mode == 0) {
                // c in [0,3072): s = which of q/k/v, h = head, d = dim
                int s = c >> 10;
                int hc = c & 1023;
                int h = hc >> 6, d = hc & 63;
                int bi = row >> 11, n = row & 2047;
                long off = ((long)(bi * NHEAD + h) * SEQ + n) * HDIM + d;
                __hip_bfloat16 bv = __float2bfloat16(v);
                if (s == 0)      Qb[off] = bv;
                else if (s == 1) Kb[off] = bv;
                else             Vb[off] = bv;
            } else {
                Cout[(long)row * N + c] = v;
            }
        }
    }
}

// ---------------------------------------------------------------------------
// Flash-style attention, fp32 math, bf16 Q/K/V in [B*H, SEQ, HDIM].
// Block = 256 threads: thread t owns q-row r = t&63, dim group g = t>>6
// (dims g*16..g*16+15). Online softmax (m,l) replicated across the 4
// threads sharing a row (all compute identical values from shared data).
// Grid: x = 32 q-tiles, y = 64 (b*h).
// ---------------------------------------------------------------------------
__global__ __launch_bounds__(256)
void attn_kernel(const __hip_bfloat16* __restrict__ Qb,
                 const __hip_bfloat16* __restrict__ Kb,
                 const __hip_bfloat16* __restrict__ Vb,
                 float* __restrict__ O) {
    const int bh = blockIdx.y;
    const int q0 = blockIdx.x * 64;
    const int t = threadIdx.x;
    const int r = t & 63;
    const int g = t >> 6;
    const long base = (long)bh * SEQ * HDIM;

    __shared__ float Qs[64][65];
    __shared__ float Ks[64][65];
    __shared__ float Vs[64][65];
    __shared__ float Ps[64][65];
    __shared__ float red[4][64];

#pragma unroll
    for (int e = 0; e < 16; ++e) {
        int idx = e * 256 + t;
        int i = idx >> 6, d = idx & 63;
        Qs[i][d] = __bfloat162float(Qb[base + (long)(q0 + i) * HDIM + d]);
    }

    float m = -1e30f, l = 0.f;
    float o[16];
#pragma unroll
    for (int i = 0; i < 16; ++i) o[i] = 0.f;

    for (int kt = 0; kt < SEQ / 64; ++kt) {
        __syncthreads();   // previous iteration's consumers done with Ks/Vs/Ps/red
        int k0 = kt * 64;
#pragma unroll
        for (int e = 0; e < 16; ++e) {
            int idx = e * 256 + t;
            int i = idx >> 6, d = idx & 63;
            Ks[i][d] = __bfloat162float(Kb[base + (long)(k0 + i) * HDIM + d]);
            Vs[i][d] = __bfloat162float(Vb[base + (long)(k0 + i) * HDIM + d]);
        }
        __syncthreads();

        // scores for row r, cols j = g*16 .. g*16+15
        float s[16];
        float tmax = -1e30f;
#pragma unroll
        for (int jj = 0; jj < 16; ++jj) {
            int j = g * 16 + jj;
            float acc = 0.f;
#pragma unroll 8
            for (int d = 0; d < 64; ++d) acc += Qs[r][d] * Ks[j][d];
            acc *= SCALE;
            s[jj] = acc;
            tmax = fmaxf(tmax, acc);
        }
        red[g][r] = tmax;
        __syncthreads();
        float tilemax = fmaxf(fmaxf(red[0][r], red[1][r]),
                              fmaxf(red[2][r], red[3][r]));
        float mnew = fmaxf(m, tilemax);
        float corr = __expf(m - mnew);
        float tsum = 0.f;
#pragma unroll
        for (int jj = 0; jj < 16; ++jj) {
            float p = __expf(s[jj] - mnew);
            s[jj] = p;
            tsum += p;
        }
        __syncthreads();   // everyone done reading red (max phase)
        red[g][r] = tsum;
#pragma unroll
        for (int jj = 0; jj < 16; ++jj) Ps[r][g * 16 + jj] = s[jj];
        __syncthreads();
        float tilesum = red[0][r] + red[1][r] + red[2][r] + red[3][r];
        l = l * corr + tilesum;
        m = mnew;
#pragma unroll
        for (int dd = 0; dd < 16; ++dd) o[dd] *= corr;
        // PV: o[r][g*16+dd] += sum_j P[r][j] * V[j][g*16+dd]
        for (int j = 0; j < 64; ++j) {
            float pv = Ps[r][j];
#pragma unroll
            for (int dd = 0; dd < 16; ++dd) o[dd] += pv * Vs[j][g * 16 + dd];
        }
    }

    float inv = 1.f / l;
    int b = bh >> 4, h = bh & 15;
    long orow = (long)(b * SEQ + q0 + r);
    float* dst = O + orow * DIM + h * HDIM + g * 16;
#pragma unroll
    for (int dd = 0; dd < 16; ++dd) dst[dd] = o[dd] * inv;
}

// ---------------------------------------------------------------------------
extern "C" void kernel_launch(void* const* d_in, const int* in_sizes, int n_in,
                              void* d_out, int out_size, void* d_ws, size_t ws_size,
                              hipStream_t stream) {
    const float* x      = (const float*)d_in[0];   // [4,2048,1024]
    const float* W_qkv  = (const float*)d_in[1];   // [1024,3072]
    const float* b_qkv  = (const float*)d_in[2];   // [3072]
    const float* W_proj = (const float*)d_in[3];   // [1024,1024]
    const float* b_proj = (const float*)d_in[4];   // [1024]
    float* out = (float*)d_out;                    // [4,2048,1024]

    // workspace layout
    const size_t qkv_elems = (size_t)BATCH * NHEAD * SEQ * HDIM;   // 8.39M
    char* ws = (char*)d_ws;
    __hip_bfloat16* Qb = (__hip_bfloat16*)ws;
    __hip_bfloat16* Kb = (__hip_bfloat16*)(ws + qkv_elems * 2);
    __hip_bfloat16* Vb = (__hip_bfloat16*)(ws + qkv_elems * 4);
    float* attnout     = (float*)(ws + qkv_elems * 6);             // [8192,1024] f32

    dim3 blk(16, 16);
    // GEMM1: x @ W_qkv + b_qkv -> scatter Q/K/V (bf16)
    gemm_bias_kernel<<<dim3(3 * DIM / 64, ROWS / 64), blk, 0, stream>>>(
        x, W_qkv, b_qkv, ROWS, 3 * DIM, DIM, 0, Qb, Kb, Vb, nullptr);

    // Attention -> attnout [B,N,H*hd] (f32)
    attn_kernel<<<dim3(SEQ / 64, BATCH * NHEAD), 256, 0, stream>>>(
        Qb, Kb, Vb, attnout);

    // GEMM2: attnout @ W_proj + b_proj -> out (f32)
    gemm_bias_kernel<<<dim3(DIM / 64, ROWS / 64), blk, 0, stream>>>(
        attnout, W_proj, b_proj, ROWS, DIM, DIM, 1, nullptr, nullptr, nullptr, out);
}

// Round 2
// 1538.294 us; speedup vs baseline: 2.6948x; 2.6948x over previous
//
#include <hip/hip_runtime.h>
#include <hip/hip_bf16.h>

#define BATCH 4
#define SEQ   2048
#define DIM   1024
#define NHEAD 16
#define HDIM  64
#define ROWS  (BATCH * SEQ)        // 8192
#define SCALE 0.125f               // 64^-0.5
#define LS    68                   // LDS row stride (bf16 elems): 64 + 4 pad

typedef __bf16 bf16x8 __attribute__((ext_vector_type(8)));
typedef float  f32x4  __attribute__((ext_vector_type(4)));

// ---------------------------------------------------------------------------
// Tiled fp32 GEMM (unchanged from R0): C = A@B + bias
// mode 0: scatter into Q/K/V bf16 [B,H,N,64]; mode 1: fp32 store
// ---------------------------------------------------------------------------
__global__ __launch_bounds__(256)
void gemm_bias_kernel(const float* __restrict__ A, const float* __restrict__ B,
                      const float* __restrict__ bias,
                      int M, int N, int K, int mode,
                      __hip_bfloat16* __restrict__ Qb,
                      __hip_bfloat16* __restrict__ Kb,
                      __hip_bfloat16* __restrict__ Vb,
                      float* __restrict__ Cout) {
    const int tx = threadIdx.x, ty = threadIdx.y;
    const int t = ty * 16 + tx;
    const int row0 = blockIdx.y * 64;
    const int col0 = blockIdx.x * 64;

    __shared__ float As[16][65];
    __shared__ float Bs[16][65];

    float acc[4][4];
#pragma unroll
    for (int i = 0; i < 4; ++i)
#pragma unroll
        for (int j = 0; j < 4; ++j) acc[i][j] = 0.f;

    for (int k0 = 0; k0 < K; k0 += 16) {
#pragma unroll
        for (int e = 0; e < 4; ++e) {
            int idx = e * 256 + t;
            {
                int i = idx >> 4, kk = idx & 15;
                As[kk][i] = A[(long)(row0 + i) * K + (k0 + kk)];
            }
            {
                int kk = idx >> 6, j = idx & 63;
                Bs[kk][j] = B[(long)(k0 + kk) * N + (col0 + j)];
            }
        }
        __syncthreads();
#pragma unroll
        for (int kk = 0; kk < 16; ++kk) {
            float a[4], b[4];
#pragma unroll
            for (int i = 0; i < 4; ++i) a[i] = As[kk][ty * 4 + i];
#pragma unroll
            for (int j = 0; j < 4; ++j) b[j] = Bs[kk][tx * 4 + j];
#pragma unroll
            for (int i = 0; i < 4; ++i)
#pragma unroll
                for (int j = 0; j < 4; ++j) acc[i][j] += a[i] * b[j];
        }
        __syncthreads();
    }

#pragma unroll
    for (int i = 0; i < 4; ++i) {
#pragma unroll
        for (int j = 0; j < 4; ++j) {
            int row = row0 + ty * 4 + i;
            int c = col0 + tx * 4 + j;
            float v = acc[i][j] + bias[c];
            if (mode == 0) {
                int s = c >> 10;
                int hc = c & 1023;
                int h = hc >> 6, d = hc & 63;
                int bi = row >> 11, n = row & 2047;
                long off = ((long)(bi * NHEAD + h) * SEQ + n) * HDIM + d;
                __hip_bfloat16 bv = __float2bfloat16(v);
                if (s == 0)      Qb[off] = bv;
                else if (s == 1) Kb[off] = bv;
                else             Vb[off] = bv;
            } else {
                Cout[(long)row * N + c] = v;
            }
        }
    }
}

// ---------------------------------------------------------------------------
// MFMA flash attention, bf16 inputs in [B*H, SEQ, 64].
// Block = 256 thr (4 waves). Q-tile 64 rows (16/wave). K-tile 64.
// Per wave, per k-tile: 8 QK^T MFMAs (16x16x32) + 8 PV MFMAs.
// Layouts rely only on the verified C/D mapping (col=lane&15,
// row=4*(lane>>4)+reg); A/B k-permutation cancels because both operands
// are always read as 8 contiguous elems along the contraction axis.
// ---------------------------------------------------------------------------
__global__ __launch_bounds__(256)
void attn_mfma_kernel(const ushort* __restrict__ Qg,
                      const ushort* __restrict__ Kg,
                      const ushort* __restrict__ Vg,
                      float* __restrict__ O) {
    const int bh = blockIdx.y;
    const int q0 = blockIdx.x * 64;
    const int tt = threadIdx.x;
    const int w  = tt >> 6;        // wave 0..3
    const int l  = tt & 63;
    const int c  = l & 15;
    const int g  = l >> 4;         // 0..3
    const size_t base = (size_t)bh * SEQ * HDIM;

    __shared__ ushort Ks[64][LS];      // K tile, row-major [kpos][d]
    __shared__ ushort Vt[64][LS];      // V tile transposed [d][kpos]
    __shared__ ushort Ps[4][16][LS];   // wave-private P [qrow][kpos]

    // staging coords
    const int sr = tt >> 3;        // 0..31
    const int sa = tt & 7;         // 0..7

    // Q fragments: lane holds row (l&15), d = 32*ds + 8*g + e
    bf16x8 qf[2];
#pragma unroll
    for (int ds = 0; ds < 2; ++ds) {
        uint4 raw = *(const uint4*)(Qg + base + (size_t)(q0 + 16 * w + c) * HDIM
                                    + 32 * ds + 8 * g);
        qf[ds] = __builtin_bit_cast(bf16x8, raw);
    }

    f32x4 o[4];
#pragma unroll
    for (int dcol = 0; dcol < 4; ++dcol) o[dcol] = (f32x4){0.f, 0.f, 0.f, 0.f};
    float m0[4], l0[4];
#pragma unroll
    for (int r = 0; r < 4; ++r) { m0[r] = -1e30f; l0[r] = 0.f; }

    for (int kt = 0; kt < SEQ / 64; ++kt) {
        const int k0 = kt * 64;
        __syncthreads();   // all waves done reading Ks/Vt of prev tile
        // ---- stage K (row-major) ----
#pragma unroll
        for (int i = 0; i < 2; ++i) {
            int row = i * 32 + sr;
            uint4 raw = *(const uint4*)(Kg + base + (size_t)(k0 + row) * HDIM + 8 * sa);
            *(uint2*)&Ks[row][8 * sa]     = make_uint2(raw.x, raw.y);
            *(uint2*)&Ks[row][8 * sa + 4] = make_uint2(raw.z, raw.w);
        }
        // ---- stage V transposed (pair-packed b32 writes) ----
        {
            int kp0 = 2 * sr;
            uint4 r0 = *(const uint4*)(Vg + base + (size_t)(k0 + kp0) * HDIM + 8 * sa);
            uint4 r1 = *(const uint4*)(Vg + base + (size_t)(k0 + kp0 + 1) * HDIM + 8 * sa);
            const uint* a0 = (const uint*)&r0;
            const uint* a1 = (const uint*)&r1;
#pragma unroll
            for (int e = 0; e < 8; ++e) {
                uint lo = (e & 1) ? (a0[e >> 1] >> 16) : (a0[e >> 1] & 0xffffu);
                uint hi = (e & 1) ? (a1[e >> 1] >> 16) : (a1[e >> 1] & 0xffffu);
                *(uint*)&Vt[8 * sa + e][kp0] = lo | (hi << 16);
            }
        }
        __syncthreads();

        // ---- QK^T: 4 kpos-subtiles of 16, each K=64 over 2 MFMAs ----
        float s[4][4];
#pragma unroll
        for (int kp = 0; kp < 4; ++kp) {
            f32x4 acc = (f32x4){0.f, 0.f, 0.f, 0.f};
#pragma unroll
            for (int ds = 0; ds < 2; ++ds) {
                uint2 b0 = *(const uint2*)&Ks[kp * 16 + c][32 * ds + 8 * g];
                uint2 b1 = *(const uint2*)&Ks[kp * 16 + c][32 * ds + 8 * g + 4];
                uint4 braw = make_uint4(b0.x, b0.y, b1.x, b1.y);
                acc = __builtin_amdgcn_mfma_f32_16x16x32_bf16(
                        qf[ds], __builtin_bit_cast(bf16x8, braw), acc, 0, 0, 0);
            }
#pragma unroll
            for (int r = 0; r < 4; ++r) s[kp][r] = acc[r] * SCALE;
        }

        // ---- online softmax (lane owns q-rows 4g+r, col c of each kp) ----
        float tm[4], corr[4], rs[4];
#pragma unroll
        for (int r = 0; r < 4; ++r)
            tm[r] = fmaxf(fmaxf(s[0][r], s[1][r]), fmaxf(s[2][r], s[3][r]));
#pragma unroll
        for (int mask = 1; mask <= 8; mask <<= 1)
#pragma unroll
            for (int r = 0; r < 4; ++r)
                tm[r] = fmaxf(tm[r], __shfl_xor(tm[r], mask, 64));
#pragma unroll
        for (int r = 0; r < 4; ++r) {
            float mn = fmaxf(m0[r], tm[r]);
            corr[r] = __expf(m0[r] - mn);
            m0[r] = mn;
            float p0 = __expf(s[0][r] - mn), p1 = __expf(s[1][r] - mn);
            float p2 = __expf(s[2][r] - mn), p3 = __expf(s[3][r] - mn);
            s[0][r] = p0; s[1][r] = p1; s[2][r] = p2; s[3][r] = p3;
            rs[r] = (p0 + p1) + (p2 + p3);
        }
#pragma unroll
        for (int mask = 1; mask <= 8; mask <<= 1)
#pragma unroll
            for (int r = 0; r < 4; ++r)
                rs[r] += __shfl_xor(rs[r], mask, 64);
#pragma unroll
        for (int r = 0; r < 4; ++r) l0[r] = l0[r] * corr[r] + rs[r];

        // ---- write P (bf16) to wave-private LDS from D-layout ----
#pragma unroll
        for (int kp = 0; kp < 4; ++kp)
#pragma unroll
            for (int r = 0; r < 4; ++r) {
                __bf16 hb = (__bf16)s[kp][r];
                Ps[w][4 * g + r][kp * 16 + c] = __builtin_bit_cast(ushort, hb);
            }

        // ---- rescale O ----
#pragma unroll
        for (int dcol = 0; dcol < 4; ++dcol)
#pragma unroll
            for (int r = 0; r < 4; ++r) o[dcol][r] *= corr[r];

        // ---- PV: A = P rows, B = Vt rows ----
#pragma unroll
        for (int ks = 0; ks < 2; ++ks) {
            uint2 p0 = *(const uint2*)&Ps[w][c][32 * ks + 8 * g];
            uint2 p1 = *(const uint2*)&Ps[w][c][32 * ks + 8 * g + 4];
            bf16x8 pf = __builtin_bit_cast(bf16x8, make_uint4(p0.x, p0.y, p1.x, p1.y));
#pragma unroll
            for (int dcol = 0; dcol < 4; ++dcol) {
                uint2 v0 = *(const uint2*)&Vt[16 * dcol + c][32 * ks + 8 * g];
                uint2 v1 = *(const uint2*)&Vt[16 * dcol + c][32 * ks + 8 * g + 4];
                o[dcol] = __builtin_amdgcn_mfma_f32_16x16x32_bf16(
                            pf, __builtin_bit_cast(bf16x8, make_uint4(v0.x, v0.y, v1.x, v1.y)),
                            o[dcol], 0, 0, 0);
            }
        }
    }

    // ---- epilogue: divide by l, store fp32 ----
    const int b = bh >> 4, h = bh & 15;
#pragma unroll
    for (int r = 0; r < 4; ++r) {
        float inv = 1.f / l0[r];
        int q = q0 + 16 * w + 4 * g + r;
#pragma unroll
        for (int dcol = 0; dcol < 4; ++dcol) {
            O[(size_t)(b * SEQ + q) * DIM + h * HDIM + 16 * dcol + c] = o[dcol][r] * inv;
        }
    }
}

// ---------------------------------------------------------------------------
extern "C" void kernel_launch(void* const* d_in, const int* in_sizes, int n_in,
                              void* d_out, int out_size, void* d_ws, size_t ws_size,
                              hipStream_t stream) {
    const float* x      = (const float*)d_in[0];
    const float* W_qkv  = (const float*)d_in[1];
    const float* b_qkv  = (const float*)d_in[2];
    const float* W_proj = (const float*)d_in[3];
    const float* b_proj = (const float*)d_in[4];
    float* out = (float*)d_out;

    const size_t qkv_elems = (size_t)BATCH * NHEAD * SEQ * HDIM;   // 8.39M
    char* ws = (char*)d_ws;
    __hip_bfloat16* Qb = (__hip_bfloat16*)ws;
    __hip_bfloat16* Kb = (__hip_bfloat16*)(ws + qkv_elems * 2);
    __hip_bfloat16* Vb = (__hip_bfloat16*)(ws + qkv_elems * 4);
    float* attnout     = (float*)(ws + qkv_elems * 6);             // [8192,1024] f32

    dim3 blk(16, 16);
    gemm_bias_kernel<<<dim3(3 * DIM / 64, ROWS / 64), blk, 0, stream>>>(
        x, W_qkv, b_qkv, ROWS, 3 * DIM, DIM, 0, Qb, Kb, Vb, nullptr);

    attn_mfma_kernel<<<dim3(SEQ / 64, BATCH * NHEAD), 256, 0, stream>>>(
        (const ushort*)Qb, (const ushort*)Kb, (const ushort*)Vb, attnout);

    gemm_bias_kernel<<<dim3(DIM / 64, ROWS / 64), blk, 0, stream>>>(
        attnout, W_proj, b_proj, ROWS, DIM, DIM, 1, nullptr, nullptr, nullptr, out);
}

// Round 3
// 368.413 us; speedup vs baseline: 11.2519x; 4.1755x over previous
//
#include <hip/hip_runtime.h>
#include <hip/hip_bf16.h>

#define BATCH 4
#define SEQ   2048
#define DIM   1024
#define NHEAD 16
#define HDIM  64
#define ROWS  (BATCH * SEQ)        // 8192
#define SCALE 0.125f               // 64^-0.5
#define LS    68                   // attn LDS row stride (bf16 elems)
#define GLS   68                   // gemm LDS row stride (BK=64 + 4 pad)

typedef __bf16 bf16x8 __attribute__((ext_vector_type(8)));
typedef float  f32x4  __attribute__((ext_vector_type(4)));

// ---------------------------------------------------------------------------
// prep kernels: f32 -> bf16 convert, and f32 -> bf16 transpose
// ---------------------------------------------------------------------------
__global__ __launch_bounds__(256)
void convert_bf16_kernel(const float* __restrict__ in, ushort* __restrict__ out, int n8) {
    int stride = gridDim.x * blockDim.x;
    for (int i = blockIdx.x * blockDim.x + threadIdx.x; i < n8; i += stride) {
        float4 a = ((const float4*)in)[2 * i];
        float4 b = ((const float4*)in)[2 * i + 1];
        ushort u[8];
        u[0] = __builtin_bit_cast(ushort, (__bf16)a.x);
        u[1] = __builtin_bit_cast(ushort, (__bf16)a.y);
        u[2] = __builtin_bit_cast(ushort, (__bf16)a.z);
        u[3] = __builtin_bit_cast(ushort, (__bf16)a.w);
        u[4] = __builtin_bit_cast(ushort, (__bf16)b.x);
        u[5] = __builtin_bit_cast(ushort, (__bf16)b.y);
        u[6] = __builtin_bit_cast(ushort, (__bf16)b.z);
        u[7] = __builtin_bit_cast(ushort, (__bf16)b.w);
        ((uint4*)out)[i] = *(uint4*)u;
    }
}

// W [K,N] f32 -> Wt [N,K] bf16
__global__ __launch_bounds__(256)
void transpose_bf16_kernel(const float* __restrict__ W, ushort* __restrict__ Wt,
                           int K, int N) {
    __shared__ float tile[32][33];
    const int tx = threadIdx.x, ty = threadIdx.y;   // (32, 8)
    const int n0 = blockIdx.x * 32, k0 = blockIdx.y * 32;
#pragma unroll
    for (int i = 0; i < 4; ++i)
        tile[ty + 8 * i][tx] = W[(long)(k0 + ty + 8 * i) * N + n0 + tx];
    __syncthreads();
#pragma unroll
    for (int i = 0; i < 4; ++i) {
        float v = tile[tx][ty + 8 * i];
        Wt[(long)(n0 + ty + 8 * i) * K + k0 + tx] = __builtin_bit_cast(ushort, (__bf16)v);
    }
}

// ---------------------------------------------------------------------------
// bf16 MFMA GEMM: C[M,N] = A[M,K] @ Bt[N,K]^T + bias
// 128x128 tile, BK=64, 4 waves (2x2), per-wave 4x4 frags of 16x16x32.
// mode 0: scatter to Q/K/V bf16 [B,H,N,64]; mode 1: fp32 store to Cout.
// Both operand fragments are loaded contraction-contiguous (8 elems at
// 8*g) so the per-lane k-permutation cancels; C/D mapping is the verified
// col=lane&15, row=4*(lane>>4)+reg.
// ---------------------------------------------------------------------------
__global__ __launch_bounds__(256)
void gemm_mfma_kernel(const ushort* __restrict__ A, const ushort* __restrict__ Bt,
                      const float* __restrict__ bias,
                      int M, int N, int K, int mode,
                      __hip_bfloat16* __restrict__ Qb,
                      __hip_bfloat16* __restrict__ Kb,
                      __hip_bfloat16* __restrict__ Vb,
                      float* __restrict__ Cout) {
    const int t  = threadIdx.x;
    const int w  = t >> 6;
    const int l  = t & 63;
    const int c  = l & 15;
    const int g  = l >> 4;
    const int wr = w >> 1, wc = w & 1;
    const int row0 = blockIdx.y * 128;
    const int col0 = blockIdx.x * 128;

    __shared__ ushort As[128][GLS];
    __shared__ ushort Bs[128][GLS];

    const int sr = t >> 3;     // 0..31
    const int sa = t & 7;      // 0..7

    f32x4 acc[4][4];
#pragma unroll
    for (int i = 0; i < 4; ++i)
#pragma unroll
        for (int j = 0; j < 4; ++j) acc[i][j] = (f32x4){0.f, 0.f, 0.f, 0.f};

    for (int k0 = 0; k0 < K; k0 += 64) {
        __syncthreads();
#pragma unroll
        for (int i = 0; i < 4; ++i) {
            int row = i * 32 + sr;
            uint4 a = *(const uint4*)(A + (size_t)(row0 + row) * K + k0 + 8 * sa);
            *(uint2*)&As[row][8 * sa]     = make_uint2(a.x, a.y);
            *(uint2*)&As[row][8 * sa + 4] = make_uint2(a.z, a.w);
            uint4 b = *(const uint4*)(Bt + (size_t)(col0 + row) * K + k0 + 8 * sa);
            *(uint2*)&Bs[row][8 * sa]     = make_uint2(b.x, b.y);
            *(uint2*)&Bs[row][8 * sa + 4] = make_uint2(b.z, b.w);
        }
        __syncthreads();

#pragma unroll
        for (int ks = 0; ks < 2; ++ks) {
            bf16x8 am[4], bn[4];
#pragma unroll
            for (int mt = 0; mt < 4; ++mt) {
                uint2 a0 = *(const uint2*)&As[wr * 64 + mt * 16 + c][ks * 32 + 8 * g];
                uint2 a1 = *(const uint2*)&As[wr * 64 + mt * 16 + c][ks * 32 + 8 * g + 4];
                am[mt] = __builtin_bit_cast(bf16x8, make_uint4(a0.x, a0.y, a1.x, a1.y));
            }
#pragma unroll
            for (int nt = 0; nt < 4; ++nt) {
                uint2 b0 = *(const uint2*)&Bs[wc * 64 + nt * 16 + c][ks * 32 + 8 * g];
                uint2 b1 = *(const uint2*)&Bs[wc * 64 + nt * 16 + c][ks * 32 + 8 * g + 4];
                bn[nt] = __builtin_bit_cast(bf16x8, make_uint4(b0.x, b0.y, b1.x, b1.y));
            }
#pragma unroll
            for (int mt = 0; mt < 4; ++mt)
#pragma unroll
                for (int nt = 0; nt < 4; ++nt)
                    acc[mt][nt] = __builtin_amdgcn_mfma_f32_16x16x32_bf16(
                        am[mt], bn[nt], acc[mt][nt], 0, 0, 0);
        }
    }

    // epilogue
    float bv[4];
#pragma unroll
    for (int nt = 0; nt < 4; ++nt) bv[nt] = bias[col0 + wc * 64 + nt * 16 + c];

#pragma unroll
    for (int mt = 0; mt < 4; ++mt) {
#pragma unroll
        for (int r = 0; r < 4; ++r) {
            int grow = row0 + wr * 64 + mt * 16 + 4 * g + r;
#pragma unroll
            for (int nt = 0; nt < 4; ++nt) {
                int gcol = col0 + wc * 64 + nt * 16 + c;
                float v = acc[mt][nt][r] + bv[nt];
                if (mode == 0) {
                    int s = gcol >> 10;
                    int hc = gcol & 1023;
                    int h = hc >> 6, d = hc & 63;
                    int bi = grow >> 11, n = grow & 2047;
                    size_t off = ((size_t)(bi * NHEAD + h) * SEQ + n) * HDIM + d;
                    __hip_bfloat16 hb = __float2bfloat16(v);
                    if (s == 0)      Qb[off] = hb;
                    else if (s == 1) Kb[off] = hb;
                    else             Vb[off] = hb;
                } else {
                    Cout[(size_t)grow * N + gcol] = v;
                }
            }
        }
    }
}

// ---------------------------------------------------------------------------
// MFMA flash attention (verified in R2), now storing bf16 output.
// ---------------------------------------------------------------------------
__global__ __launch_bounds__(256)
void attn_mfma_kernel(const ushort* __restrict__ Qg,
                      const ushort* __restrict__ Kg,
                      const ushort* __restrict__ Vg,
                      ushort* __restrict__ O) {
    const int bh = blockIdx.y;
    const int q0 = blockIdx.x * 64;
    const int tt = threadIdx.x;
    const int w  = tt >> 6;
    const int l  = tt & 63;
    const int c  = l & 15;
    const int g  = l >> 4;
    const size_t base = (size_t)bh * SEQ * HDIM;

    __shared__ ushort Ks[64][LS];
    __shared__ ushort Vt[64][LS];
    __shared__ ushort Ps[4][16][LS];

    const int sr = tt >> 3;
    const int sa = tt & 7;

    bf16x8 qf[2];
#pragma unroll
    for (int ds = 0; ds < 2; ++ds) {
        uint4 raw = *(const uint4*)(Qg + base + (size_t)(q0 + 16 * w + c) * HDIM
                                    + 32 * ds + 8 * g);
        qf[ds] = __builtin_bit_cast(bf16x8, raw);
    }

    f32x4 o[4];
#pragma unroll
    for (int dcol = 0; dcol < 4; ++dcol) o[dcol] = (f32x4){0.f, 0.f, 0.f, 0.f};
    float m0[4], l0[4];
#pragma unroll
    for (int r = 0; r < 4; ++r) { m0[r] = -1e30f; l0[r] = 0.f; }

    for (int kt = 0; kt < SEQ / 64; ++kt) {
        const int k0 = kt * 64;
        __syncthreads();
#pragma unroll
        for (int i = 0; i < 2; ++i) {
            int row = i * 32 + sr;
            uint4 raw = *(const uint4*)(Kg + base + (size_t)(k0 + row) * HDIM + 8 * sa);
            *(uint2*)&Ks[row][8 * sa]     = make_uint2(raw.x, raw.y);
            *(uint2*)&Ks[row][8 * sa + 4] = make_uint2(raw.z, raw.w);
        }
        {
            int kp0 = 2 * sr;
            uint4 r0 = *(const uint4*)(Vg + base + (size_t)(k0 + kp0) * HDIM + 8 * sa);
            uint4 r1 = *(const uint4*)(Vg + base + (size_t)(k0 + kp0 + 1) * HDIM + 8 * sa);
            const uint* a0 = (const uint*)&r0;
            const uint* a1 = (const uint*)&r1;
#pragma unroll
            for (int e = 0; e < 8; ++e) {
                uint lo = (e & 1) ? (a0[e >> 1] >> 16) : (a0[e >> 1] & 0xffffu);
                uint hi = (e & 1) ? (a1[e >> 1] >> 16) : (a1[e >> 1] & 0xffffu);
                *(uint*)&Vt[8 * sa + e][kp0] = lo | (hi << 16);
            }
        }
        __syncthreads();

        float s[4][4];
#pragma unroll
        for (int kp = 0; kp < 4; ++kp) {
            f32x4 accs = (f32x4){0.f, 0.f, 0.f, 0.f};
#pragma unroll
            for (int ds = 0; ds < 2; ++ds) {
                uint2 b0 = *(const uint2*)&Ks[kp * 16 + c][32 * ds + 8 * g];
                uint2 b1 = *(const uint2*)&Ks[kp * 16 + c][32 * ds + 8 * g + 4];
                uint4 braw = make_uint4(b0.x, b0.y, b1.x, b1.y);
                accs = __builtin_amdgcn_mfma_f32_16x16x32_bf16(
                        qf[ds], __builtin_bit_cast(bf16x8, braw), accs, 0, 0, 0);
            }
#pragma unroll
            for (int r = 0; r < 4; ++r) s[kp][r] = accs[r] * SCALE;
        }

        float tm[4], corr[4], rs[4];
#pragma unroll
        for (int r = 0; r < 4; ++r)
            tm[r] = fmaxf(fmaxf(s[0][r], s[1][r]), fmaxf(s[2][r], s[3][r]));
#pragma unroll
        for (int mask = 1; mask <= 8; mask <<= 1)
#pragma unroll
            for (int r = 0; r < 4; ++r)
                tm[r] = fmaxf(tm[r], __shfl_xor(tm[r], mask, 64));
#pragma unroll
        for (int r = 0; r < 4; ++r) {
            float mn = fmaxf(m0[r], tm[r]);
            corr[r] = __expf(m0[r] - mn);
            m0[r] = mn;
            float p0 = __expf(s[0][r] - mn), p1 = __expf(s[1][r] - mn);
            float p2 = __expf(s[2][r] - mn), p3 = __expf(s[3][r] - mn);
            s[0][r] = p0; s[1][r] = p1; s[2][r] = p2; s[3][r] = p3;
            rs[r] = (p0 + p1) + (p2 + p3);
        }
#pragma unroll
        for (int mask = 1; mask <= 8; mask <<= 1)
#pragma unroll
            for (int r = 0; r < 4; ++r)
                rs[r] += __shfl_xor(rs[r], mask, 64);
#pragma unroll
        for (int r = 0; r < 4; ++r) l0[r] = l0[r] * corr[r] + rs[r];

#pragma unroll
        for (int kp = 0; kp < 4; ++kp)
#pragma unroll
            for (int r = 0; r < 4; ++r) {
                __bf16 hb = (__bf16)s[kp][r];
                Ps[w][4 * g + r][kp * 16 + c] = __builtin_bit_cast(ushort, hb);
            }

#pragma unroll
        for (int dcol = 0; dcol < 4; ++dcol)
#pragma unroll
            for (int r = 0; r < 4; ++r) o[dcol][r] *= corr[r];

#pragma unroll
        for (int ks = 0; ks < 2; ++ks) {
            uint2 p0 = *(const uint2*)&Ps[w][c][32 * ks + 8 * g];
            uint2 p1 = *(const uint2*)&Ps[w][c][32 * ks + 8 * g + 4];
            bf16x8 pf = __builtin_bit_cast(bf16x8, make_uint4(p0.x, p0.y, p1.x, p1.y));
#pragma unroll
            for (int dcol = 0; dcol < 4; ++dcol) {
                uint2 v0 = *(const uint2*)&Vt[16 * dcol + c][32 * ks + 8 * g];
                uint2 v1 = *(const uint2*)&Vt[16 * dcol + c][32 * ks + 8 * g + 4];
                o[dcol] = __builtin_amdgcn_mfma_f32_16x16x32_bf16(
                            pf, __builtin_bit_cast(bf16x8, make_uint4(v0.x, v0.y, v1.x, v1.y)),
                            o[dcol], 0, 0, 0);
            }
        }
    }

    const int b = bh >> 4, h = bh & 15;
#pragma unroll
    for (int r = 0; r < 4; ++r) {
        float inv = 1.f / l0[r];
        int q = q0 + 16 * w + 4 * g + r;
#pragma unroll
        for (int dcol = 0; dcol < 4; ++dcol) {
            __bf16 hb = (__bf16)(o[dcol][r] * inv);
            O[(size_t)(b * SEQ + q) * DIM + h * HDIM + 16 * dcol + c] =
                __builtin_bit_cast(ushort, hb);
        }
    }
}

// ---------------------------------------------------------------------------
extern "C" void kernel_launch(void* const* d_in, const int* in_sizes, int n_in,
                              void* d_out, int out_size, void* d_ws, size_t ws_size,
                              hipStream_t stream) {
    const float* x      = (const float*)d_in[0];
    const float* W_qkv  = (const float*)d_in[1];
    const float* b_qkv  = (const float*)d_in[2];
    const float* W_proj = (const float*)d_in[3];
    const float* b_proj = (const float*)d_in[4];
    float* out = (float*)d_out;

    const size_t qkv_elems = (size_t)BATCH * NHEAD * SEQ * HDIM;   // 8.39M
    char* ws = (char*)d_ws;
    // layout (bytes):
    ushort* xb      = (ushort*)ws;                                  // 16.8MB (reused as attnout)
    ushort* Wqkv_t  = (ushort*)(ws + qkv_elems * 2);                // 6.3MB
    ushort* Wproj_t = (ushort*)(ws + qkv_elems * 2 + (size_t)DIM * 3 * DIM * 2);
    char*   ws2     = ws + qkv_elems * 2 + (size_t)DIM * 3 * DIM * 2 + (size_t)DIM * DIM * 2;
    __hip_bfloat16* Qb = (__hip_bfloat16*)ws2;
    __hip_bfloat16* Kb = (__hip_bfloat16*)(ws2 + qkv_elems * 2);
    __hip_bfloat16* Vb = (__hip_bfloat16*)(ws2 + qkv_elems * 4);
    ushort* attnout = xb;   // WAR-safe: gemm1 finishes with xb before attn writes

    // prep: convert + transpose
    convert_bf16_kernel<<<2048, 256, 0, stream>>>(x, xb, ROWS * DIM / 8);
    transpose_bf16_kernel<<<dim3(3 * DIM / 32, DIM / 32), dim3(32, 8), 0, stream>>>(
        W_qkv, Wqkv_t, DIM, 3 * DIM);
    transpose_bf16_kernel<<<dim3(DIM / 32, DIM / 32), dim3(32, 8), 0, stream>>>(
        W_proj, Wproj_t, DIM, DIM);

    // GEMM1: xb @ Wqkv + bias -> scatter Q/K/V bf16
    gemm_mfma_kernel<<<dim3(3 * DIM / 128, ROWS / 128), 256, 0, stream>>>(
        xb, Wqkv_t, b_qkv, ROWS, 3 * DIM, DIM, 0, Qb, Kb, Vb, nullptr);

    // attention -> attnout bf16
    attn_mfma_kernel<<<dim3(SEQ / 64, BATCH * NHEAD), 256, 0, stream>>>(
        (const ushort*)Qb, (const ushort*)Kb, (const ushort*)Vb, attnout);

    // GEMM2: attnout @ Wproj + bias -> out fp32
    gemm_mfma_kernel<<<dim3(DIM / 128, ROWS / 128), 256, 0, stream>>>(
        attnout, Wproj_t, b_proj, ROWS, DIM, DIM, 1, nullptr, nullptr, nullptr, out);
}

// Round 4
// 245.225 us; speedup vs baseline: 16.9042x; 1.5023x over previous
//
#include <hip/hip_runtime.h>
#include <hip/hip_bf16.h>

#define BATCH 4
#define SEQ   2048
#define DIM   1024
#define NHEAD 16
#define HDIM  64
#define ROWS  (BATCH * SEQ)        // 8192
#define LS    68                   // attn LDS row stride (bf16 elems)
#define GLS   68                   // gemm LDS row stride

typedef __bf16 bf16x8 __attribute__((ext_vector_type(8)));
typedef float  f32x4  __attribute__((ext_vector_type(4)));
typedef float  f32x16 __attribute__((ext_vector_type(16)));

// pack two f32 -> one u32 of 2 bf16 (compiler emits v_cvt_pk_bf16_f32)
static __device__ __forceinline__ uint pack2(float a, float b) {
    ushort ua = __builtin_bit_cast(ushort, (__bf16)a);
    ushort ub = __builtin_bit_cast(ushort, (__bf16)b);
    return (uint)ua | ((uint)ub << 16);
}
// swap a's upper 32 lanes with b's lower 32 lanes
#define PLSWAP(a, b) asm volatile("v_permlane32_swap_b32 %0, %1" : "+v"(a), "+v"(b))

// ---------------------------------------------------------------------------
// prep kernels (unchanged from R3)
// ---------------------------------------------------------------------------
__global__ __launch_bounds__(256)
void convert_bf16_kernel(const float* __restrict__ in, ushort* __restrict__ out, int n8) {
    int stride = gridDim.x * blockDim.x;
    for (int i = blockIdx.x * blockDim.x + threadIdx.x; i < n8; i += stride) {
        float4 a = ((const float4*)in)[2 * i];
        float4 b = ((const float4*)in)[2 * i + 1];
        ushort u[8];
        u[0] = __builtin_bit_cast(ushort, (__bf16)a.x);
        u[1] = __builtin_bit_cast(ushort, (__bf16)a.y);
        u[2] = __builtin_bit_cast(ushort, (__bf16)a.z);
        u[3] = __builtin_bit_cast(ushort, (__bf16)a.w);
        u[4] = __builtin_bit_cast(ushort, (__bf16)b.x);
        u[5] = __builtin_bit_cast(ushort, (__bf16)b.y);
        u[6] = __builtin_bit_cast(ushort, (__bf16)b.z);
        u[7] = __builtin_bit_cast(ushort, (__bf16)b.w);
        ((uint4*)out)[i] = *(uint4*)u;
    }
}

__global__ __launch_bounds__(256)
void transpose_bf16_kernel(const float* __restrict__ W, ushort* __restrict__ Wt,
                           int K, int N) {
    __shared__ float tile[32][33];
    const int tx = threadIdx.x, ty = threadIdx.y;   // (32, 8)
    const int n0 = blockIdx.x * 32, k0 = blockIdx.y * 32;
#pragma unroll
    for (int i = 0; i < 4; ++i)
        tile[ty + 8 * i][tx] = W[(long)(k0 + ty + 8 * i) * N + n0 + tx];
    __syncthreads();
#pragma unroll
    for (int i = 0; i < 4; ++i) {
        float v = tile[tx][ty + 8 * i];
        Wt[(long)(n0 + ty + 8 * i) * K + k0 + tx] = __builtin_bit_cast(ushort, (__bf16)v);
    }
}

// ---------------------------------------------------------------------------
// bf16 MFMA GEMM (unchanged from R3 except: mode 0 scales Q by 0.125)
// ---------------------------------------------------------------------------
__global__ __launch_bounds__(256)
void gemm_mfma_kernel(const ushort* __restrict__ A, const ushort* __restrict__ Bt,
                      const float* __restrict__ bias,
                      int M, int N, int K, int mode,
                      __hip_bfloat16* __restrict__ Qb,
                      __hip_bfloat16* __restrict__ Kb,
                      __hip_bfloat16* __restrict__ Vb,
                      float* __restrict__ Cout) {
    const int t  = threadIdx.x;
    const int w  = t >> 6;
    const int l  = t & 63;
    const int c  = l & 15;
    const int g  = l >> 4;
    const int wr = w >> 1, wc = w & 1;
    const int row0 = blockIdx.y * 128;
    const int col0 = blockIdx.x * 128;

    __shared__ ushort As[128][GLS];
    __shared__ ushort Bs[128][GLS];

    const int sr = t >> 3;
    const int sa = t & 7;

    f32x4 acc[4][4];
#pragma unroll
    for (int i = 0; i < 4; ++i)
#pragma unroll
        for (int j = 0; j < 4; ++j) acc[i][j] = (f32x4){0.f, 0.f, 0.f, 0.f};

    for (int k0 = 0; k0 < K; k0 += 64) {
        __syncthreads();
#pragma unroll
        for (int i = 0; i < 4; ++i) {
            int row = i * 32 + sr;
            uint4 a = *(const uint4*)(A + (size_t)(row0 + row) * K + k0 + 8 * sa);
            *(uint2*)&As[row][8 * sa]     = make_uint2(a.x, a.y);
            *(uint2*)&As[row][8 * sa + 4] = make_uint2(a.z, a.w);
            uint4 b = *(const uint4*)(Bt + (size_t)(col0 + row) * K + k0 + 8 * sa);
            *(uint2*)&Bs[row][8 * sa]     = make_uint2(b.x, b.y);
            *(uint2*)&Bs[row][8 * sa + 4] = make_uint2(b.z, b.w);
        }
        __syncthreads();

#pragma unroll
        for (int ks = 0; ks < 2; ++ks) {
            bf16x8 am[4], bn[4];
#pragma unroll
            for (int mt = 0; mt < 4; ++mt) {
                uint2 a0 = *(const uint2*)&As[wr * 64 + mt * 16 + c][ks * 32 + 8 * g];
                uint2 a1 = *(const uint2*)&As[wr * 64 + mt * 16 + c][ks * 32 + 8 * g + 4];
                am[mt] = __builtin_bit_cast(bf16x8, make_uint4(a0.x, a0.y, a1.x, a1.y));
            }
#pragma unroll
            for (int nt = 0; nt < 4; ++nt) {
                uint2 b0 = *(const uint2*)&Bs[wc * 64 + nt * 16 + c][ks * 32 + 8 * g];
                uint2 b1 = *(const uint2*)&Bs[wc * 64 + nt * 16 + c][ks * 32 + 8 * g + 4];
                bn[nt] = __builtin_bit_cast(bf16x8, make_uint4(b0.x, b0.y, b1.x, b1.y));
            }
#pragma unroll
            for (int mt = 0; mt < 4; ++mt)
#pragma unroll
                for (int nt = 0; nt < 4; ++nt)
                    acc[mt][nt] = __builtin_amdgcn_mfma_f32_16x16x32_bf16(
                        am[mt], bn[nt], acc[mt][nt], 0, 0, 0);
        }
    }

    float bv[4];
#pragma unroll
    for (int nt = 0; nt < 4; ++nt) bv[nt] = bias[col0 + wc * 64 + nt * 16 + c];

#pragma unroll
    for (int mt = 0; mt < 4; ++mt) {
#pragma unroll
        for (int r = 0; r < 4; ++r) {
            int grow = row0 + wr * 64 + mt * 16 + 4 * g + r;
#pragma unroll
            for (int nt = 0; nt < 4; ++nt) {
                int gcol = col0 + wc * 64 + nt * 16 + c;
                float v = acc[mt][nt][r] + bv[nt];
                if (mode == 0) {
                    int s = gcol >> 10;
                    int hc = gcol & 1023;
                    int h = hc >> 6, d = hc & 63;
                    int bi = grow >> 11, n = grow & 2047;
                    size_t off = ((size_t)(bi * NHEAD + h) * SEQ + n) * HDIM + d;
                    if (s == 0) v *= 0.125f;   // fold softmax scale into Q (exact)
                    __hip_bfloat16 hb = __float2bfloat16(v);
                    if (s == 0)      Qb[off] = hb;
                    else if (s == 1) Kb[off] = hb;
                    else             Vb[off] = hb;
                } else {
                    Cout[(size_t)grow * N + gcol] = v;
                }
            }
        }
    }
}

// ---------------------------------------------------------------------------
// MFMA flash attention v2: 4 waves x 32 q-rows, 32x32x16 MFMAs, swapped
// QK^T (lane owns one q-row => in-register softmax), swapped PV (output
// col = own q-row => per-lane rescale), T12 pack via permlane32_swap,
// T13 defer-max, double-buffered K/V with early load issue.
// Grid: 1024 blocks 1D; bh grouped 8-per-XCD for L2 locality.
// ---------------------------------------------------------------------------
__global__ __launch_bounds__(256)
void attn_mfma2_kernel(const ushort* __restrict__ Qg,
                       const ushort* __restrict__ Kg,
                       const ushort* __restrict__ Vg,
                       ushort* __restrict__ O) {
    const int id  = blockIdx.x;
    const int bh  = (id & 7) * 8 + ((id >> 3) & 7);   // XCD c owns bh [8c,8c+8)
    const int qt  = id >> 6;
    const int t   = threadIdx.x;
    const int w   = t >> 6, l = t & 63;
    const int lo5 = l & 31, hi = l >> 5;
    const size_t base = (size_t)bh * SEQ * HDIM;
    const int q0  = qt * 128 + w * 32;

    __shared__ ushort Ks[2][64 * LS];   // [kpos][d]
    __shared__ ushort Vt[2][64 * LS];   // [d][kpos]

    // Q fragments (B-operand): lane q-row = q0+lo5, d = 16*db + 8*hi + e
    bf16x8 qf[4];
    {
        const ushort* qrow = Qg + base + (size_t)(q0 + lo5) * HDIM + 8 * hi;
#pragma unroll
        for (int db = 0; db < 4; ++db)
            qf[db] = __builtin_bit_cast(bf16x8, *(const uint4*)(qrow + 16 * db));
    }

    // staging coords
    const int ksr = t & 63, kch = t >> 6;       // K: row ksr, cols 16*kch..+15
    const int vkp = t & 31, vcg = t >> 5;       // V: rows 2vkp..+1, cols 8*vcg..+7
    const ushort* Kptr = Kg + base + (size_t)ksr * HDIM + 16 * kch;
    const ushort* Vptr = Vg + base + (size_t)(2 * vkp) * HDIM + 8 * vcg;

    uint4 kr0, kr1, vr0, vr1;
    kr0 = *(const uint4*)(Kptr);
    kr1 = *(const uint4*)(Kptr + 8);
    vr0 = *(const uint4*)(Vptr);
    vr1 = *(const uint4*)(Vptr + HDIM);

    auto stageK = [&](int buf, uint4 a, uint4 b) {
        ushort* p = &Ks[buf][ksr * LS + 16 * kch];
        *(uint2*)(p)      = make_uint2(a.x, a.y);
        *(uint2*)(p + 4)  = make_uint2(a.z, a.w);
        *(uint2*)(p + 8)  = make_uint2(b.x, b.y);
        *(uint2*)(p + 12) = make_uint2(b.z, b.w);
    };
    auto stageV = [&](int buf, uint4 a, uint4 b) {
        const uint* pa = (const uint*)&a;
        const uint* pb = (const uint*)&b;
#pragma unroll
        for (int e = 0; e < 8; ++e) {
            uint vlo = (e & 1) ? (pa[e >> 1] >> 16) : (pa[e >> 1] & 0xffffu);
            uint vhi = (e & 1) ? (pb[e >> 1] >> 16) : (pb[e >> 1] & 0xffffu);
            *(uint*)&Vt[buf][(8 * vcg + e) * LS + 2 * vkp] = vlo | (vhi << 16);
        }
    };
    stageK(0, kr0, kr1);
    stageV(0, vr0, vr1);
    __syncthreads();

    f32x16 o0, o1;
#pragma unroll
    for (int r = 0; r < 16; ++r) { o0[r] = 0.f; o1[r] = 0.f; }
    float m0 = -1e30f, ll = 0.f;

    for (int kt = 0; kt < 32; ++kt) {
        const int cur = kt & 1;
        // issue next-tile global loads (land under this tile's compute)
        if (kt < 31) {
            const size_t off = (size_t)(kt + 1) * 64 * HDIM;
            kr0 = *(const uint4*)(Kptr + off);
            kr1 = *(const uint4*)(Kptr + off + 8);
            vr0 = *(const uint4*)(Vptr + off);
            vr1 = *(const uint4*)(Vptr + off + HDIM);
        }

        // ---- QK^T (swapped): D[kpos][q], A=K rows, B=Q rows ----
        f32x16 s[2];
#pragma unroll
        for (int kb = 0; kb < 2; ++kb) {
            f32x16 acc;
#pragma unroll
            for (int r = 0; r < 16; ++r) acc[r] = 0.f;
#pragma unroll
            for (int db = 0; db < 4; ++db) {
                const ushort* ap = &Ks[cur][(kb * 32 + lo5) * LS + 16 * db + 8 * hi];
                uint2 a0 = *(const uint2*)(ap);
                uint2 a1 = *(const uint2*)(ap + 4);
                bf16x8 af = __builtin_bit_cast(bf16x8, make_uint4(a0.x, a0.y, a1.x, a1.y));
                acc = __builtin_amdgcn_mfma_f32_32x32x16_bf16(af, qf[db], acc, 0, 0, 0);
            }
            s[kb] = acc;
        }

        // ---- in-register online softmax (lane owns q-row lo5) ----
        float pmax = s[0][0];
#pragma unroll
        for (int r = 1; r < 16; ++r) pmax = fmaxf(pmax, s[0][r]);
#pragma unroll
        for (int r = 0; r < 16; ++r) pmax = fmaxf(pmax, s[1][r]);
        pmax = fmaxf(pmax, __shfl_xor(pmax, 32, 64));

        if (!__all(pmax <= m0 + 8.f)) {            // T13 defer-max
            float mn = fmaxf(m0, pmax);
            float corr = __expf(m0 - mn);
#pragma unroll
            for (int r = 0; r < 16; ++r) { o0[r] *= corr; o1[r] *= corr; }
            ll *= corr;
            m0 = mn;
        }
        float rs = 0.f;
#pragma unroll
        for (int r = 0; r < 16; ++r) { float p = __expf(s[0][r] - m0); s[0][r] = p; rs += p; }
#pragma unroll
        for (int r = 0; r < 16; ++r) { float p = __expf(s[1][r] - m0); s[1][r] = p; rs += p; }
        rs += __shfl_xor(rs, 32, 64);
        ll += rs;

        // ---- T12: pack P rows into PV B-fragments (k = 16*kkblk + 8*hi + e) ----
        bf16x8 pbf[4];
#pragma unroll
        for (int kb = 0; kb < 2; ++kb)
#pragma unroll
            for (int kk = 0; kk < 2; ++kk) {
                const int b0 = kk * 8;
                uint w0 = pack2(s[kb][b0 + 0], s[kb][b0 + 1]);
                uint w1 = pack2(s[kb][b0 + 2], s[kb][b0 + 3]);
                uint w2 = pack2(s[kb][b0 + 4], s[kb][b0 + 5]);
                uint w3 = pack2(s[kb][b0 + 6], s[kb][b0 + 7]);
                PLSWAP(w0, w2);
                PLSWAP(w1, w3);
                pbf[kb * 2 + kk] = __builtin_bit_cast(bf16x8, make_uint4(w0, w1, w2, w3));
            }

        // ---- PV (swapped): D[d][q], A=V^T rows, B=P rows ----
#pragma unroll
        for (int kb = 0; kb < 2; ++kb)
#pragma unroll
            for (int kk = 0; kk < 2; ++kk) {
                const int kcol = kb * 32 + kk * 16 + 8 * hi;
                const ushort* vp0 = &Vt[cur][lo5 * LS + kcol];
                uint2 v0 = *(const uint2*)(vp0);
                uint2 v1 = *(const uint2*)(vp0 + 4);
                bf16x8 vf0 = __builtin_bit_cast(bf16x8, make_uint4(v0.x, v0.y, v1.x, v1.y));
                o0 = __builtin_amdgcn_mfma_f32_32x32x16_bf16(vf0, pbf[kb * 2 + kk], o0, 0, 0, 0);
                const ushort* vp1 = vp0 + 32 * LS;
                uint2 v2 = *(const uint2*)(vp1);
                uint2 v3 = *(const uint2*)(vp1 + 4);
                bf16x8 vf1 = __builtin_bit_cast(bf16x8, make_uint4(v2.x, v2.y, v3.x, v3.y));
                o1 = __builtin_amdgcn_mfma_f32_32x32x16_bf16(vf1, pbf[kb * 2 + kk], o1, 0, 0, 0);
            }

        __syncthreads();
        if (kt < 31) {
            stageK(cur ^ 1, kr0, kr1);
            stageV(cur ^ 1, vr0, vr1);
        }
        __syncthreads();
    }

    // ---- epilogue: per-lane divide, pack bf16, store own q-row ----
    const float inv = 1.f / ll;
    const int b = bh >> 4, h = bh & 15;
    ushort* orow = O + (size_t)(b * SEQ + q0 + lo5) * DIM + h * HDIM;
#pragma unroll
    for (int j = 0; j < 4; ++j) {
        uint2 st;
        st.x = pack2(o0[4 * j + 0] * inv, o0[4 * j + 1] * inv);
        st.y = pack2(o0[4 * j + 2] * inv, o0[4 * j + 3] * inv);
        *(uint2*)(orow + 8 * j + 4 * hi) = st;
        st.x = pack2(o1[4 * j + 0] * inv, o1[4 * j + 1] * inv);
        st.y = pack2(o1[4 * j + 2] * inv, o1[4 * j + 3] * inv);
        *(uint2*)(orow + 32 + 8 * j + 4 * hi) = st;
    }
}

// ---------------------------------------------------------------------------
extern "C" void kernel_launch(void* const* d_in, const int* in_sizes, int n_in,
                              void* d_out, int out_size, void* d_ws, size_t ws_size,
                              hipStream_t stream) {
    const float* x      = (const float*)d_in[0];
    const float* W_qkv  = (const float*)d_in[1];
    const float* b_qkv  = (const float*)d_in[2];
    const float* W_proj = (const float*)d_in[3];
    const float* b_proj = (const float*)d_in[4];
    float* out = (float*)d_out;

    const size_t qkv_elems = (size_t)BATCH * NHEAD * SEQ * HDIM;   // 8.39M
    char* ws = (char*)d_ws;
    ushort* xb      = (ushort*)ws;                                  // reused as attnout
    ushort* Wqkv_t  = (ushort*)(ws + qkv_elems * 2);
    ushort* Wproj_t = (ushort*)(ws + qkv_elems * 2 + (size_t)DIM * 3 * DIM * 2);
    char*   ws2     = ws + qkv_elems * 2 + (size_t)DIM * 3 * DIM * 2 + (size_t)DIM * DIM * 2;
    __hip_bfloat16* Qb = (__hip_bfloat16*)ws2;
    __hip_bfloat16* Kb = (__hip_bfloat16*)(ws2 + qkv_elems * 2);
    __hip_bfloat16* Vb = (__hip_bfloat16*)(ws2 + qkv_elems * 4);
    ushort* attnout = xb;   // WAR-safe: gemm1 finishes with xb before attn writes

    convert_bf16_kernel<<<2048, 256, 0, stream>>>(x, xb, ROWS * DIM / 8);
    transpose_bf16_kernel<<<dim3(3 * DIM / 32, DIM / 32), dim3(32, 8), 0, stream>>>(
        W_qkv, Wqkv_t, DIM, 3 * DIM);
    transpose_bf16_kernel<<<dim3(DIM / 32, DIM / 32), dim3(32, 8), 0, stream>>>(
        W_proj, Wproj_t, DIM, DIM);

    gemm_mfma_kernel<<<dim3(3 * DIM / 128, ROWS / 128), 256, 0, stream>>>(
        xb, Wqkv_t, b_qkv, ROWS, 3 * DIM, DIM, 0, Qb, Kb, Vb, nullptr);

    attn_mfma2_kernel<<<dim3(1024), 256, 0, stream>>>(
        (const ushort*)Qb, (const ushort*)Kb, (const ushort*)Vb, attnout);

    gemm_mfma_kernel<<<dim3(DIM / 128, ROWS / 128), 256, 0, stream>>>(
        attnout, Wproj_t, b_proj, ROWS, DIM, DIM, 1, nullptr, nullptr, nullptr, out);
}

// Round 6
// 237.727 us; speedup vs baseline: 17.4374x; 1.0315x over previous
//
#include <hip/hip_runtime.h>
#include <hip/hip_bf16.h>

#define BATCH 4
#define SEQ   2048
#define DIM   1024
#define NHEAD 16
#define HDIM  64
#define ROWS  (BATCH * SEQ)        // 8192
#define LS    68                   // attn LDS row stride (bf16 elems)
#define GLS   68                   // gemm LDS row stride
#define QSCALE 0.18033688011f      // 0.125 * log2(e): softmax in exp2 domain

typedef __bf16 bf16x8 __attribute__((ext_vector_type(8)));
typedef float  f32x4  __attribute__((ext_vector_type(4)));
typedef float  f32x16 __attribute__((ext_vector_type(16)));

// pack two f32 -> one u32 of 2 bf16 (compiler emits v_cvt_pk_bf16_f32)
static __device__ __forceinline__ uint pack2(float a, float b) {
    ushort ua = __builtin_bit_cast(ushort, (__bf16)a);
    ushort ub = __builtin_bit_cast(ushort, (__bf16)b);
    return (uint)ua | ((uint)ub << 16);
}
// swap a's upper 32 lanes with b's lower 32 lanes
#define PLSWAP(a, b) asm volatile("v_permlane32_swap_b32 %0, %1" : "+v"(a), "+v"(b))

// ---------------------------------------------------------------------------
// prep kernels (unchanged from R3/R4)
// ---------------------------------------------------------------------------
__global__ __launch_bounds__(256)
void convert_bf16_kernel(const float* __restrict__ in, ushort* __restrict__ out, int n8) {
    int stride = gridDim.x * blockDim.x;
    for (int i = blockIdx.x * blockDim.x + threadIdx.x; i < n8; i += stride) {
        float4 a = ((const float4*)in)[2 * i];
        float4 b = ((const float4*)in)[2 * i + 1];
        ushort u[8];
        u[0] = __builtin_bit_cast(ushort, (__bf16)a.x);
        u[1] = __builtin_bit_cast(ushort, (__bf16)a.y);
        u[2] = __builtin_bit_cast(ushort, (__bf16)a.z);
        u[3] = __builtin_bit_cast(ushort, (__bf16)a.w);
        u[4] = __builtin_bit_cast(ushort, (__bf16)b.x);
        u[5] = __builtin_bit_cast(ushort, (__bf16)b.y);
        u[6] = __builtin_bit_cast(ushort, (__bf16)b.z);
        u[7] = __builtin_bit_cast(ushort, (__bf16)b.w);
        ((uint4*)out)[i] = *(uint4*)u;
    }
}

__global__ __launch_bounds__(256)
void transpose_bf16_kernel(const float* __restrict__ W, ushort* __restrict__ Wt,
                           int K, int N) {
    __shared__ float tile[32][33];
    const int tx = threadIdx.x, ty = threadIdx.y;   // (32, 8)
    const int n0 = blockIdx.x * 32, k0 = blockIdx.y * 32;
#pragma unroll
    for (int i = 0; i < 4; ++i)
        tile[ty + 8 * i][tx] = W[(long)(k0 + ty + 8 * i) * N + n0 + tx];
    __syncthreads();
#pragma unroll
    for (int i = 0; i < 4; ++i) {
        float v = tile[tx][ty + 8 * i];
        Wt[(long)(n0 + ty + 8 * i) * K + k0 + tx] = __builtin_bit_cast(ushort, (__bf16)v);
    }
}

// ---------------------------------------------------------------------------
// bf16 MFMA GEMM (mode 0 scales Q by 0.125*log2e for exp2-domain softmax)
// ---------------------------------------------------------------------------
__global__ __launch_bounds__(256)
void gemm_mfma_kernel(const ushort* __restrict__ A, const ushort* __restrict__ Bt,
                      const float* __restrict__ bias,
                      int M, int N, int K, int mode,
                      __hip_bfloat16* __restrict__ Qb,
                      __hip_bfloat16* __restrict__ Kb,
                      __hip_bfloat16* __restrict__ Vb,
                      float* __restrict__ Cout) {
    const int t  = threadIdx.x;
    const int w  = t >> 6;
    const int l  = t & 63;
    const int c  = l & 15;
    const int g  = l >> 4;
    const int wr = w >> 1, wc = w & 1;
    const int row0 = blockIdx.y * 128;
    const int col0 = blockIdx.x * 128;

    __shared__ ushort As[128][GLS];
    __shared__ ushort Bs[128][GLS];

    const int sr = t >> 3;
    const int sa = t & 7;

    f32x4 acc[4][4];
#pragma unroll
    for (int i = 0; i < 4; ++i)
#pragma unroll
        for (int j = 0; j < 4; ++j) acc[i][j] = (f32x4){0.f, 0.f, 0.f, 0.f};

    for (int k0 = 0; k0 < K; k0 += 64) {
        __syncthreads();
#pragma unroll
        for (int i = 0; i < 4; ++i) {
            int row = i * 32 + sr;
            uint4 a = *(const uint4*)(A + (size_t)(row0 + row) * K + k0 + 8 * sa);
            *(uint2*)&As[row][8 * sa]     = make_uint2(a.x, a.y);
            *(uint2*)&As[row][8 * sa + 4] = make_uint2(a.z, a.w);
            uint4 b = *(const uint4*)(Bt + (size_t)(col0 + row) * K + k0 + 8 * sa);
            *(uint2*)&Bs[row][8 * sa]     = make_uint2(b.x, b.y);
            *(uint2*)&Bs[row][8 * sa + 4] = make_uint2(b.z, b.w);
        }
        __syncthreads();

#pragma unroll
        for (int ks = 0; ks < 2; ++ks) {
            bf16x8 am[4], bn[4];
#pragma unroll
            for (int mt = 0; mt < 4; ++mt) {
                uint2 a0 = *(const uint2*)&As[wr * 64 + mt * 16 + c][ks * 32 + 8 * g];
                uint2 a1 = *(const uint2*)&As[wr * 64 + mt * 16 + c][ks * 32 + 8 * g + 4];
                am[mt] = __builtin_bit_cast(bf16x8, make_uint4(a0.x, a0.y, a1.x, a1.y));
            }
#pragma unroll
            for (int nt = 0; nt < 4; ++nt) {
                uint2 b0 = *(const uint2*)&Bs[wc * 64 + nt * 16 + c][ks * 32 + 8 * g];
                uint2 b1 = *(const uint2*)&Bs[wc * 64 + nt * 16 + c][ks * 32 + 8 * g + 4];
                bn[nt] = __builtin_bit_cast(bf16x8, make_uint4(b0.x, b0.y, b1.x, b1.y));
            }
#pragma unroll
            for (int mt = 0; mt < 4; ++mt)
#pragma unroll
                for (int nt = 0; nt < 4; ++nt)
                    acc[mt][nt] = __builtin_amdgcn_mfma_f32_16x16x32_bf16(
                        am[mt], bn[nt], acc[mt][nt], 0, 0, 0);
        }
    }

    float bv[4];
#pragma unroll
    for (int nt = 0; nt < 4; ++nt) bv[nt] = bias[col0 + wc * 64 + nt * 16 + c];

#pragma unroll
    for (int mt = 0; mt < 4; ++mt) {
#pragma unroll
        for (int r = 0; r < 4; ++r) {
            int grow = row0 + wr * 64 + mt * 16 + 4 * g + r;
#pragma unroll
            for (int nt = 0; nt < 4; ++nt) {
                int gcol = col0 + wc * 64 + nt * 16 + c;
                float v = acc[mt][nt][r] + bv[nt];
                if (mode == 0) {
                    int s = gcol >> 10;
                    int hc = gcol & 1023;
                    int h = hc >> 6, d = hc & 63;
                    int bi = grow >> 11, n = grow & 2047;
                    size_t off = ((size_t)(bi * NHEAD + h) * SEQ + n) * HDIM + d;
                    if (s == 0) v *= QSCALE;   // fold scale + log2e into Q (exp2 domain)
                    __hip_bfloat16 hb = __float2bfloat16(v);
                    if (s == 0)      Qb[off] = hb;
                    else if (s == 1) Kb[off] = hb;
                    else             Vb[off] = hb;
                } else {
                    Cout[(size_t)grow * N + gcol] = v;
                }
            }
        }
    }
}

// ---------------------------------------------------------------------------
// MFMA flash attention v2b: exact R4 structure (verified) + exp2-domain
// softmax + T5 setprio around MFMA clusters. V staged via verified
// bit-pack transpose; P packed via cvt_pk + permlane32_swap (T12);
// defer-max (T13); double-buffered K/V with early load issue (T14-lite).
// ---------------------------------------------------------------------------
__global__ __launch_bounds__(256)
void attn_mfma2_kernel(const ushort* __restrict__ Qg,
                       const ushort* __restrict__ Kg,
                       const ushort* __restrict__ Vg,
                       ushort* __restrict__ O) {
    const int id  = blockIdx.x;
    const int bh  = (id & 7) * 8 + ((id >> 3) & 7);   // XCD c owns bh [8c,8c+8)
    const int qt  = id >> 6;
    const int t   = threadIdx.x;
    const int w   = t >> 6, l = t & 63;
    const int lo5 = l & 31, hi = l >> 5;
    const size_t base = (size_t)bh * SEQ * HDIM;
    const int q0  = qt * 128 + w * 32;

    __shared__ ushort Ks[2][64 * LS];   // [kpos][d]
    __shared__ ushort Vt[2][64 * LS];   // [d][kpos]

    // Q fragments (B-operand): lane q-row = q0+lo5, d = 16*db + 8*hi + e
    bf16x8 qf[4];
    {
        const ushort* qrow = Qg + base + (size_t)(q0 + lo5) * HDIM + 8 * hi;
#pragma unroll
        for (int db = 0; db < 4; ++db)
            qf[db] = __builtin_bit_cast(bf16x8, *(const uint4*)(qrow + 16 * db));
    }

    // staging coords
    const int ksr = t & 63, kch = t >> 6;       // K: row ksr, cols 16*kch..+15
    const int vkp = t & 31, vcg = t >> 5;       // V: rows 2vkp..+1, cols 8*vcg..+7
    const ushort* Kptr = Kg + base + (size_t)ksr * HDIM + 16 * kch;
    const ushort* Vptr = Vg + base + (size_t)(2 * vkp) * HDIM + 8 * vcg;

    uint4 kr0, kr1, vr0, vr1;
    kr0 = *(const uint4*)(Kptr);
    kr1 = *(const uint4*)(Kptr + 8);
    vr0 = *(const uint4*)(Vptr);
    vr1 = *(const uint4*)(Vptr + HDIM);

    auto stageK = [&](int buf, uint4 a, uint4 b) {
        ushort* p = &Ks[buf][ksr * LS + 16 * kch];
        *(uint2*)(p)      = make_uint2(a.x, a.y);
        *(uint2*)(p + 4)  = make_uint2(a.z, a.w);
        *(uint2*)(p + 8)  = make_uint2(b.x, b.y);
        *(uint2*)(p + 12) = make_uint2(b.z, b.w);
    };
    auto stageV = [&](int buf, uint4 a, uint4 b) {
        const uint* pa = (const uint*)&a;
        const uint* pb = (const uint*)&b;
#pragma unroll
        for (int e = 0; e < 8; ++e) {
            uint vlo = (e & 1) ? (pa[e >> 1] >> 16) : (pa[e >> 1] & 0xffffu);
            uint vhi = (e & 1) ? (pb[e >> 1] >> 16) : (pb[e >> 1] & 0xffffu);
            *(uint*)&Vt[buf][(8 * vcg + e) * LS + 2 * vkp] = vlo | (vhi << 16);
        }
    };
    stageK(0, kr0, kr1);
    stageV(0, vr0, vr1);
    __syncthreads();

    f32x16 o0, o1;
#pragma unroll
    for (int r = 0; r < 16; ++r) { o0[r] = 0.f; o1[r] = 0.f; }
    float m0 = -1e30f, ll = 0.f;

    for (int kt = 0; kt < 32; ++kt) {
        const int cur = kt & 1;
        // issue next-tile global loads (land under this tile's compute)
        if (kt < 31) {
            const size_t off = (size_t)(kt + 1) * 64 * HDIM;
            kr0 = *(const uint4*)(Kptr + off);
            kr1 = *(const uint4*)(Kptr + off + 8);
            vr0 = *(const uint4*)(Vptr + off);
            vr1 = *(const uint4*)(Vptr + off + HDIM);
        }

        // ---- QK^T (swapped): D[kpos][q], A=K rows, B=Q rows ----
        f32x16 s[2];
        __builtin_amdgcn_s_setprio(1);
#pragma unroll
        for (int kb = 0; kb < 2; ++kb) {
            f32x16 acc;
#pragma unroll
            for (int r = 0; r < 16; ++r) acc[r] = 0.f;
#pragma unroll
            for (int db = 0; db < 4; ++db) {
                const ushort* ap = &Ks[cur][(kb * 32 + lo5) * LS + 16 * db + 8 * hi];
                uint2 a0 = *(const uint2*)(ap);
                uint2 a1 = *(const uint2*)(ap + 4);
                bf16x8 af = __builtin_bit_cast(bf16x8, make_uint4(a0.x, a0.y, a1.x, a1.y));
                acc = __builtin_amdgcn_mfma_f32_32x32x16_bf16(af, qf[db], acc, 0, 0, 0);
            }
            s[kb] = acc;
        }
        __builtin_amdgcn_s_setprio(0);

        // ---- in-register online softmax, exp2 domain (lane owns q-row) ----
        float pmax = s[0][0];
#pragma unroll
        for (int r = 1; r < 16; ++r) pmax = fmaxf(pmax, s[0][r]);
#pragma unroll
        for (int r = 0; r < 16; ++r) pmax = fmaxf(pmax, s[1][r]);
        pmax = fmaxf(pmax, __shfl_xor(pmax, 32, 64));

        if (!__all(pmax <= m0 + 8.f)) {            // T13 defer-max (P <= 2^8)
            float mn = fmaxf(m0, pmax);
            float corr = __builtin_amdgcn_exp2f(m0 - mn);
#pragma unroll
            for (int r = 0; r < 16; ++r) { o0[r] *= corr; o1[r] *= corr; }
            ll *= corr;
            m0 = mn;
        }
        float rs = 0.f;
#pragma unroll
        for (int r = 0; r < 16; ++r) {
            float p = __builtin_amdgcn_exp2f(s[0][r] - m0); s[0][r] = p; rs += p;
        }
#pragma unroll
        for (int r = 0; r < 16; ++r) {
            float p = __builtin_amdgcn_exp2f(s[1][r] - m0); s[1][r] = p; rs += p;
        }
        rs += __shfl_xor(rs, 32, 64);
        ll += rs;

        // ---- T12: pack P rows into PV B-fragments (k = 16*kkblk + 8*hi + e) ----
        bf16x8 pbf[4];
#pragma unroll
        for (int kb = 0; kb < 2; ++kb)
#pragma unroll
            for (int kk = 0; kk < 2; ++kk) {
                const int b0 = kk * 8;
                uint w0 = pack2(s[kb][b0 + 0], s[kb][b0 + 1]);
                uint w1 = pack2(s[kb][b0 + 2], s[kb][b0 + 3]);
                uint w2 = pack2(s[kb][b0 + 4], s[kb][b0 + 5]);
                uint w3 = pack2(s[kb][b0 + 6], s[kb][b0 + 7]);
                PLSWAP(w0, w2);
                PLSWAP(w1, w3);
                pbf[kb * 2 + kk] = __builtin_bit_cast(bf16x8, make_uint4(w0, w1, w2, w3));
            }

        // ---- PV (swapped): D[d][q], A=V^T rows, B=P rows ----
        __builtin_amdgcn_s_setprio(1);
#pragma unroll
        for (int kb = 0; kb < 2; ++kb)
#pragma unroll
            for (int kk = 0; kk < 2; ++kk) {
                const int kcol = kb * 32 + kk * 16 + 8 * hi;
                const ushort* vp0 = &Vt[cur][lo5 * LS + kcol];
                uint2 v0 = *(const uint2*)(vp0);
                uint2 v1 = *(const uint2*)(vp0 + 4);
                bf16x8 vf0 = __builtin_bit_cast(bf16x8, make_uint4(v0.x, v0.y, v1.x, v1.y));
                o0 = __builtin_amdgcn_mfma_f32_32x32x16_bf16(vf0, pbf[kb * 2 + kk], o0, 0, 0, 0);
                const ushort* vp1 = vp0 + 32 * LS;
                uint2 v2 = *(const uint2*)(vp1);
                uint2 v3 = *(const uint2*)(vp1 + 4);
                bf16x8 vf1 = __builtin_bit_cast(bf16x8, make_uint4(v2.x, v2.y, v3.x, v3.y));
                o1 = __builtin_amdgcn_mfma_f32_32x32x16_bf16(vf1, pbf[kb * 2 + kk], o1, 0, 0, 0);
            }
        __builtin_amdgcn_s_setprio(0);

        __syncthreads();
        if (kt < 31) {
            stageK(cur ^ 1, kr0, kr1);
            stageV(cur ^ 1, vr0, vr1);
        }
        __syncthreads();
    }

    // ---- epilogue: per-lane divide, pack bf16, store own q-row ----
    const float inv = 1.f / ll;
    const int b = bh >> 4, h = bh & 15;
    ushort* orow = O + (size_t)(b * SEQ + q0 + lo5) * DIM + h * HDIM;
#pragma unroll
    for (int j = 0; j < 4; ++j) {
        uint2 st;
        st.x = pack2(o0[4 * j + 0] * inv, o0[4 * j + 1] * inv);
        st.y = pack2(o0[4 * j + 2] * inv, o0[4 * j + 3] * inv);
        *(uint2*)(orow + 8 * j + 4 * hi) = st;
        st.x = pack2(o1[4 * j + 0] * inv, o1[4 * j + 1] * inv);
        st.y = pack2(o1[4 * j + 2] * inv, o1[4 * j + 3] * inv);
        *(uint2*)(orow + 32 + 8 * j + 4 * hi) = st;
    }
}

// ---------------------------------------------------------------------------
extern "C" void kernel_launch(void* const* d_in, const int* in_sizes, int n_in,
                              void* d_out, int out_size, void* d_ws, size_t ws_size,
                              hipStream_t stream) {
    const float* x      = (const float*)d_in[0];
    const float* W_qkv  = (const float*)d_in[1];
    const float* b_qkv  = (const float*)d_in[2];
    const float* W_proj = (const float*)d_in[3];
    const float* b_proj = (const float*)d_in[4];
    float* out = (float*)d_out;

    const size_t qkv_elems = (size_t)BATCH * NHEAD * SEQ * HDIM;   // 8.39M
    char* ws = (char*)d_ws;
    ushort* xb      = (ushort*)ws;                                  // reused as attnout
    ushort* Wqkv_t  = (ushort*)(ws + qkv_elems * 2);
    ushort* Wproj_t = (ushort*)(ws + qkv_elems * 2 + (size_t)DIM * 3 * DIM * 2);
    char*   ws2     = ws + qkv_elems * 2 + (size_t)DIM * 3 * DIM * 2 + (size_t)DIM * DIM * 2;
    __hip_bfloat16* Qb = (__hip_bfloat16*)ws2;
    __hip_bfloat16* Kb = (__hip_bfloat16*)(ws2 + qkv_elems * 2);
    __hip_bfloat16* Vb = (__hip_bfloat16*)(ws2 + qkv_elems * 4);
    ushort* attnout = xb;   // WAR-safe: gemm1 finishes with xb before attn writes

    convert_bf16_kernel<<<2048, 256, 0, stream>>>(x, xb, ROWS * DIM / 8);
    transpose_bf16_kernel<<<dim3(3 * DIM / 32, DIM / 32), dim3(32, 8), 0, stream>>>(
        W_qkv, Wqkv_t, DIM, 3 * DIM);
    transpose_bf16_kernel<<<dim3(DIM / 32, DIM / 32), dim3(32, 8), 0, stream>>>(
        W_proj, Wproj_t, DIM, DIM);

    gemm_mfma_kernel<<<dim3(3 * DIM / 128, ROWS / 128), 256, 0, stream>>>(
        xb, Wqkv_t, b_qkv, ROWS, 3 * DIM, DIM, 0, Qb, Kb, Vb, nullptr);

    attn_mfma2_kernel<<<dim3(1024), 256, 0, stream>>>(
        (const ushort*)Qb, (const ushort*)Kb, (const ushort*)Vb, attnout);

    gemm_mfma_kernel<<<dim3(DIM / 128, ROWS / 128), 256, 0, stream>>>(
        attnout, Wproj_t, b_proj, ROWS, DIM, DIM, 1, nullptr, nullptr, nullptr, out);
}